// Round 1
// baseline (449.837 us; speedup 1.0000x reference)
//
#include <hip/hip_runtime.h>

// ---------------------------------------------------------------------------
// GIN 3-layer: h_{l+1} = act((h + agg(h)) @ W + b)
// Restructured as: z = act_in(h) @ W ; out[i] = b + z[i] + sum_{e: dst=i} z[src_e]
// (segment-sum commutes with the linear map; bias must be added AFTER agg
//  because agg would multiply it by the in-degree otherwise)
// ---------------------------------------------------------------------------

// ---- edge dtype detection: int64 (reference decl) vs int32 (JAX x64-off) ----
__global__ __launch_bounds__(256) void k_detect(const int* __restrict__ ew,
                                                int* __restrict__ flag, int E) {
  int i = blockIdx.x * 256 + threadIdx.x;   // grid=4 -> i in [0,1024)
  int idx = 2 * i + 1;
  if (idx < 2 * E) {
    if (ew[idx] != 0) atomicOr(flag, 1);    // nonzero odd word => int32 layout
  }
}

__global__ __launch_bounds__(256) void k_convert(const void* __restrict__ edges,
                                                 const int* __restrict__ flag,
                                                 int* __restrict__ src,
                                                 int* __restrict__ dst, int E) {
  int e = blockIdx.x * 256 + threadIdx.x;
  if (e >= E) return;
  if (*flag) {                               // int32 layout
    const int* p = (const int*)edges;
    src[e] = p[e];
    dst[e] = p[E + e];
  } else {                                   // int64 layout (values < 2^31)
    const long long* p = (const long long*)edges;
    src[e] = (int)p[e];
    dst[e] = (int)p[E + e];
  }
}

// ---- CSR build: histogram -> exclusive scan -> fill --------------------------
__global__ __launch_bounds__(256) void k_hist(const int* __restrict__ dst,
                                              int* __restrict__ counts, int E) {
  int e = blockIdx.x * 256 + threadIdx.x;
  if (e < E) atomicAdd(&counts[dst[e]], 1);
}

__global__ __launch_bounds__(256) void k_scan1(const int* __restrict__ counts,
                                               int* __restrict__ offs,
                                               int* __restrict__ bsum, int N) {
  __shared__ int s[256];
  int t = threadIdx.x;
  int base = blockIdx.x * 1024 + t * 4;
  int c0 = 0, c1 = 0, c2 = 0, c3 = 0;
  if (base + 0 < N) c0 = counts[base + 0];
  if (base + 1 < N) c1 = counts[base + 1];
  if (base + 2 < N) c2 = counts[base + 2];
  if (base + 3 < N) c3 = counts[base + 3];
  int mySum = c0 + c1 + c2 + c3;
  s[t] = mySum;
  __syncthreads();
  for (int d = 1; d < 256; d <<= 1) {
    int v = (t >= d) ? s[t - d] : 0;
    __syncthreads();
    s[t] += v;
    __syncthreads();
  }
  int excl = s[t] - mySum;
  if (base + 0 < N) offs[base + 0] = excl;
  if (base + 1 < N) offs[base + 1] = excl + c0;
  if (base + 2 < N) offs[base + 2] = excl + c0 + c1;
  if (base + 3 < N) offs[base + 3] = excl + c0 + c1 + c2;
  if (t == 255) bsum[blockIdx.x] = s[255];
}

__global__ void k_scan2(int* __restrict__ bsum, int nb) {
  if (threadIdx.x == 0 && blockIdx.x == 0) {
    int run = 0;
    for (int i = 0; i < nb; i++) { int v = bsum[i]; bsum[i] = run; run += v; }
  }
}

__global__ __launch_bounds__(256) void k_scan3(int* __restrict__ offs,
                                               const int* __restrict__ bsum,
                                               int* __restrict__ cursor,
                                               int N, int E) {
  int t = threadIdx.x;
  int add = bsum[blockIdx.x];
  int base = blockIdx.x * 1024 + t * 4;
#pragma unroll
  for (int j = 0; j < 4; j++) {
    int i = base + j;
    if (i < N) { int v = offs[i] + add; offs[i] = v; cursor[i] = v; }
  }
  if (blockIdx.x == 0 && t == 0) offs[N] = E;
}

__global__ __launch_bounds__(256) void k_fill(const int* __restrict__ src,
                                              const int* __restrict__ dst,
                                              int* __restrict__ cursor,
                                              int* __restrict__ csr, int E) {
  int e = blockIdx.x * 256 + threadIdx.x;
  if (e >= E) return;
  int d = dst[e];
  int pos = atomicAdd(&cursor[d], 1);
  csr[pos] = src[e];
}

// ---- fp32 GEMM: Z[M x NC] = act(A[M x 128]) @ W[128 x NC]  (no bias here) ---
// Block: 256 threads, tile 64 rows x NC cols. Thread (tx,ty) in 16x16:
// 4 rows x (NC/16) cols of accumulators.
template <int NC, bool RELU>
__global__ __launch_bounds__(256) void k_gemm(const float* __restrict__ A,
                                              const float* __restrict__ W,
                                              float* __restrict__ Z, int M) {
  constexpr int K = 128;
  constexpr int CPT = NC / 16;
  __shared__ float Alds[8][72];   // [kk][row], pad 64->72 to break bank stride
  __shared__ float Wlds[8][NC];   // [kk][col]
  int t = threadIdx.x;
  int tx = t & 15, ty = t >> 4;
  int row0 = blockIdx.x * 64;

  float acc[4][CPT];
#pragma unroll
  for (int r = 0; r < 4; r++)
#pragma unroll
    for (int c = 0; c < CPT; c++) acc[r][c] = 0.f;

  int lr = t >> 2;                 // 0..63 : row for A staging
  int lk = (t & 3) * 2;            // 0,2,4,6
  int arow = row0 + lr;
  const float* Aptr = (arow < M) ? (A + (size_t)arow * K) : nullptr;

  for (int k0 = 0; k0 < K; k0 += 8) {
    float2 av = make_float2(0.f, 0.f);
    if (Aptr) av = *(const float2*)(Aptr + k0 + lk);
    if (RELU) { av.x = fmaxf(av.x, 0.f); av.y = fmaxf(av.y, 0.f); }
    Alds[lk][lr] = av.x;
    Alds[lk + 1][lr] = av.y;

    if constexpr (NC == 128) {
      int kk = t >> 5; int c = (t & 31) * 4;
      *(float4*)&Wlds[kk][c] = *(const float4*)&W[(size_t)(k0 + kk) * NC + c];
    } else {
      int kk = t >> 5; int c = (t & 31) * 2;
      *(float2*)&Wlds[kk][c] = *(const float2*)&W[(size_t)(k0 + kk) * NC + c];
    }
    __syncthreads();

#pragma unroll
    for (int kk = 0; kk < 8; kk++) {
      float a[4];
      *(float4*)a = *(const float4*)&Alds[kk][ty * 4];
      float wv[CPT];
#pragma unroll
      for (int c4 = 0; c4 < CPT; c4 += 4)
        *(float4*)&wv[c4] = *(const float4*)&Wlds[kk][tx * CPT + c4];
#pragma unroll
      for (int r = 0; r < 4; r++)
#pragma unroll
        for (int c = 0; c < CPT; c++)
          acc[r][c] = fmaf(a[r], wv[c], acc[r][c]);
    }
    __syncthreads();
  }

#pragma unroll
  for (int r = 0; r < 4; r++) {
    int grow = row0 + ty * 4 + r;
    if (grow < M) {
#pragma unroll
      for (int c4 = 0; c4 < CPT; c4 += 4)
        *(float4*)&Z[(size_t)grow * NC + tx * CPT + c4] = *(float4*)&acc[r][c4];
    }
  }
}

// ---- CSR aggregation: out[i] = bias + z[i] + sum_{e in in(i)} z[src_e] ------
__global__ __launch_bounds__(256) void k_agg128(const float* __restrict__ z,
                                                const int* __restrict__ csr,
                                                const int* __restrict__ offs,
                                                const float* __restrict__ bias,
                                                float* __restrict__ out, int N) {
  int t = threadIdx.x;
  int node = blockIdx.x * 8 + (t >> 5);
  if (node >= N) return;
  int c = (t & 31) * 4;
  float4 v = *(const float4*)&z[(size_t)node * 128 + c];
  float4 b = *(const float4*)&bias[c];
  v.x += b.x; v.y += b.y; v.z += b.z; v.w += b.w;
  int s = offs[node], e = offs[node + 1];
  for (int j = s; j < e; j++) {
    int srci = csr[j];
    float4 u = *(const float4*)&z[(size_t)srci * 128 + c];
    v.x += u.x; v.y += u.y; v.z += u.z; v.w += u.w;
  }
  *(float4*)&out[(size_t)node * 128 + c] = v;
}

__global__ __launch_bounds__(256) void k_agg64(const float* __restrict__ z,
                                               const int* __restrict__ csr,
                                               const int* __restrict__ offs,
                                               const float* __restrict__ bias,
                                               float* __restrict__ out, int N) {
  int t = threadIdx.x;
  int node = blockIdx.x * 16 + (t >> 4);
  if (node >= N) return;
  int c = (t & 15) * 4;
  float4 v = *(const float4*)&z[(size_t)node * 64 + c];
  float4 b = *(const float4*)&bias[c];
  v.x += b.x; v.y += b.y; v.z += b.z; v.w += b.w;
  int s = offs[node], e = offs[node + 1];
  for (int j = s; j < e; j++) {
    int srci = csr[j];
    float4 u = *(const float4*)&z[(size_t)srci * 64 + c];
    v.x += u.x; v.y += u.y; v.z += u.z; v.w += u.w;
  }
  *(float4*)&out[(size_t)node * 64 + c] = v;
}

// ---------------------------------------------------------------------------
extern "C" void kernel_launch(void* const* d_in, const int* in_sizes, int n_in,
                              void* d_out, int out_size, void* d_ws, size_t ws_size,
                              hipStream_t stream) {
  const float* x  = (const float*)d_in[0];
  const void* edges = d_in[1];
  const float* W1 = (const float*)d_in[2];
  const float* b1 = (const float*)d_in[3];
  const float* W2 = (const float*)d_in[4];
  const float* b2 = (const float*)d_in[5];
  const float* W3 = (const float*)d_in[6];
  const float* b3 = (const float*)d_in[7];
  float* out = (float*)d_out;

  int N = in_sizes[0] / 128;   // 100000
  int E = in_sizes[1] / 2;     // 600000

  // workspace layout (~111 MB total)
  char* w = (char*)d_ws;
  size_t off = 0;
  auto alloc = [&](size_t bytes) -> void* {
    void* p = w + off;
    off = (off + bytes + 255) & ~(size_t)255;
    return p;
  };
  int*   flag   = (int*)alloc(4);
  int*   src32  = (int*)alloc((size_t)E * 4);
  int*   dst32  = (int*)alloc((size_t)E * 4);
  int*   csr    = (int*)alloc((size_t)E * 4);
  int*   offs   = (int*)alloc((size_t)(N + 1) * 4);
  int*   cursor = (int*)alloc((size_t)N * 4);
  int*   bsum   = (int*)alloc(4096);
  float* z      = (float*)alloc((size_t)N * 128 * 4);
  float* a      = (float*)alloc((size_t)N * 128 * 4);  // a1, reused as a2

  int ge = (E + 255) / 256;
  int nb = (N + 1023) / 1024;

  // edge normalization + CSR build (every call; ws is re-poisoned)
  hipMemsetAsync(flag, 0, 4, stream);
  k_detect<<<4, 256, 0, stream>>>((const int*)edges, flag, E);
  k_convert<<<ge, 256, 0, stream>>>(edges, flag, src32, dst32, E);
  hipMemsetAsync(cursor, 0, (size_t)N * 4, stream);
  k_hist<<<ge, 256, 0, stream>>>(dst32, cursor, E);
  k_scan1<<<nb, 256, 0, stream>>>(cursor, offs, bsum, N);
  k_scan2<<<1, 64, 0, stream>>>(bsum, nb);
  k_scan3<<<nb, 256, 0, stream>>>(offs, bsum, cursor, N, E);
  k_fill<<<ge, 256, 0, stream>>>(src32, dst32, cursor, csr, E);

  int gm = (N + 63) / 64;
  // layer 1: z = x@W1 ; a1 = b1 + z + agg(z)
  k_gemm<128, false><<<gm, 256, 0, stream>>>(x, W1, z, N);
  k_agg128<<<(N + 7) / 8, 256, 0, stream>>>(z, csr, offs, b1, a, N);
  // layer 2: z = relu(a1)@W2 ; a2 = b2 + z + agg(z)
  k_gemm<128, true><<<gm, 256, 0, stream>>>(a, W2, z, N);
  k_agg128<<<(N + 7) / 8, 256, 0, stream>>>(z, csr, offs, b2, a, N);
  // layer 3: z = relu(a2)@W3 ; out = b3 + z + agg(z)   (no final relu)
  k_gemm<64, true><<<gm, 256, 0, stream>>>(a, W3, z, N);
  k_agg64<<<(N + 15) / 16, 256, 0, stream>>>(z, csr, offs, b3, out, N);
}

// Round 2
// 394.602 us; speedup vs baseline: 1.1400x; 1.1400x over previous
//
#include <hip/hip_runtime.h>

// ---------------------------------------------------------------------------
// GIN 3-layer: h_{l+1} = act((h + agg(h)) @ W + b)
// Restructured: z = act(h) @ W ; out[i] = b + z[i] + sum_{e: dst=i} z[src_e]
// GEMM = split-bf16 MFMA (a_hi*w_hi + a_hi*w_lo + a_lo*w_hi, fp32 acc).
// ---------------------------------------------------------------------------

typedef __attribute__((ext_vector_type(8))) short short8;
typedef __attribute__((ext_vector_type(4))) float f32x4;
typedef unsigned short ushort_t;
typedef unsigned int uint_t;

__device__ inline ushort_t bf16_rne(float f) {
  uint_t u = __float_as_uint(f);
  uint_t r = (u + 0x7FFFu + ((u >> 16) & 1u)) >> 16;
  return (ushort_t)r;
}
__device__ inline float bf16_to_f32(ushort_t h) {
  return __uint_as_float(((uint_t)h) << 16);
}

// ---- edge dtype detection: int64 (reference decl) vs int32 (JAX x64-off) ----
__global__ __launch_bounds__(256) void k_detect(const int* __restrict__ ew,
                                                int* __restrict__ flag, int E) {
  int i = blockIdx.x * 256 + threadIdx.x;   // grid=4 -> i in [0,1024)
  int idx = 2 * i + 1;
  if (idx < 2 * E) {
    if (ew[idx] != 0) atomicOr(flag, 1);    // nonzero odd word => int32 layout
  }
}

// convert + fused degree histogram
__global__ __launch_bounds__(256) void k_convert(const void* __restrict__ edges,
                                                 const int* __restrict__ flag,
                                                 int* __restrict__ src,
                                                 int* __restrict__ dst,
                                                 int* __restrict__ counts, int E) {
  int e = blockIdx.x * 256 + threadIdx.x;
  if (e >= E) return;
  int s, d;
  if (*flag) {                               // int32 layout
    const int* p = (const int*)edges;
    s = p[e]; d = p[E + e];
  } else {                                   // int64 layout (values < 2^31)
    const long long* p = (const long long*)edges;
    s = (int)p[e]; d = (int)p[E + e];
  }
  src[e] = s; dst[e] = d;
  atomicAdd(&counts[d], 1);
}

// ---- CSR build: scan + fill -------------------------------------------------
__global__ __launch_bounds__(256) void k_scan1(const int* __restrict__ counts,
                                               int* __restrict__ offs,
                                               int* __restrict__ bsum, int N) {
  __shared__ int s[256];
  int t = threadIdx.x;
  int base = blockIdx.x * 1024 + t * 4;
  int c0 = 0, c1 = 0, c2 = 0, c3 = 0;
  if (base + 0 < N) c0 = counts[base + 0];
  if (base + 1 < N) c1 = counts[base + 1];
  if (base + 2 < N) c2 = counts[base + 2];
  if (base + 3 < N) c3 = counts[base + 3];
  int mySum = c0 + c1 + c2 + c3;
  s[t] = mySum;
  __syncthreads();
  for (int d = 1; d < 256; d <<= 1) {
    int v = (t >= d) ? s[t - d] : 0;
    __syncthreads();
    s[t] += v;
    __syncthreads();
  }
  int excl = s[t] - mySum;
  if (base + 0 < N) offs[base + 0] = excl;
  if (base + 1 < N) offs[base + 1] = excl + c0;
  if (base + 2 < N) offs[base + 2] = excl + c0 + c1;
  if (base + 3 < N) offs[base + 3] = excl + c0 + c1 + c2;
  if (t == 255) bsum[blockIdx.x] = s[255];
}

// parallel single-block exclusive scan of block sums (nb <= 128)
__global__ __launch_bounds__(128) void k_scan2(int* __restrict__ bsum, int nb) {
  __shared__ int s[128];
  int t = threadIdx.x;
  int v = (t < nb) ? bsum[t] : 0;
  s[t] = v;
  __syncthreads();
  for (int d = 1; d < 128; d <<= 1) {
    int u = (t >= d) ? s[t - d] : 0;
    __syncthreads();
    s[t] += u;
    __syncthreads();
  }
  if (t < nb) bsum[t] = s[t] - v;
}

__global__ __launch_bounds__(256) void k_scan3(int* __restrict__ offs,
                                               const int* __restrict__ bsum,
                                               int* __restrict__ cursor,
                                               int N, int E) {
  int t = threadIdx.x;
  int add = bsum[blockIdx.x];
  int base = blockIdx.x * 1024 + t * 4;
#pragma unroll
  for (int j = 0; j < 4; j++) {
    int i = base + j;
    if (i < N) { int v = offs[i] + add; offs[i] = v; cursor[i] = v; }
  }
  if (blockIdx.x == 0 && t == 0) offs[N] = E;
}

__global__ __launch_bounds__(256) void k_fill(const int* __restrict__ src,
                                              const int* __restrict__ dst,
                                              int* __restrict__ cursor,
                                              int* __restrict__ csr, int E) {
  int e = blockIdx.x * 256 + threadIdx.x;
  if (e >= E) return;
  int d = dst[e];
  int pos = atomicAdd(&cursor[d], 1);
  csr[pos] = src[e];
}

// ---- W repack into MFMA B-fragment order (hi/lo split bf16) -----------------
// rep[((ks*NT + tile)*64 + lane)*8 + j] = W[ks*32 + (lane>>4)*8 + j][tile*16 + (lane&15)]
__global__ __launch_bounds__(256) void k_repack(
    const float* __restrict__ W1, const float* __restrict__ W2,
    const float* __restrict__ W3,
    ushort_t* __restrict__ h1, ushort_t* __restrict__ l1,
    ushort_t* __restrict__ h2, ushort_t* __restrict__ l2,
    ushort_t* __restrict__ h3, ushort_t* __restrict__ l3) {
  int idx = blockIdx.x * 256 + threadIdx.x;
  const float* W; ushort_t* H; ushort_t* L; int NC; int i;
  if (idx < 16384)      { W = W1; H = h1; L = l1; NC = 128; i = idx; }
  else if (idx < 32768) { W = W2; H = h2; L = l2; NC = 128; i = idx - 16384; }
  else if (idx < 40960) { W = W3; H = h3; L = l3; NC = 64;  i = idx - 32768; }
  else return;
  int j = i & 7;
  int lane = (i >> 3) & 63;
  int NT = NC >> 4;
  int tile = (i >> 9) & (NT - 1);
  int ks = i >> (9 + (NC == 128 ? 3 : 2));
  int k = ks * 32 + (lane >> 4) * 8 + j;
  int n = tile * 16 + (lane & 15);
  float v = W[(size_t)k * NC + n];
  ushort_t hi = bf16_rne(v);
  ushort_t lo = bf16_rne(v - bf16_to_f32(hi));
  H[i] = hi; L[i] = lo;
}

// ---- split-bf16 MFMA GEMM: Z[M x NC] = act(A[M x 128]) @ W -----------------
// Block = 4 independent waves; wave owns 16 rows x NC cols. No LDS.
template <int NC, bool RELU>
__global__ __launch_bounds__(256) void k_gemm_mfma(
    const float* __restrict__ A, const ushort_t* __restrict__ Bhi,
    const ushort_t* __restrict__ Blo, float* __restrict__ Z, int M) {
  constexpr int NT = NC / 16;
  int lane = threadIdx.x & 63;
  int wave = threadIdx.x >> 6;
  int row0 = blockIdx.x * 64 + wave * 16;
  int m = lane & 15;
  int q = lane >> 4;
  int grow = row0 + m;                 // row of this lane's A fragment
  bool rowok = (grow < M);

  f32x4 acc[NT];
#pragma unroll
  for (int t = 0; t < NT; t++) { acc[t][0] = 0.f; acc[t][1] = 0.f; acc[t][2] = 0.f; acc[t][3] = 0.f; }

  const float* arow = A + (size_t)grow * 128 + q * 8;

#pragma unroll
  for (int ks = 0; ks < 4; ks++) {
    float av[8];
    if (rowok) {
      *(float4*)(av)     = *(const float4*)(arow + ks * 32);
      *(float4*)(av + 4) = *(const float4*)(arow + ks * 32 + 4);
    } else {
#pragma unroll
      for (int j = 0; j < 8; j++) av[j] = 0.f;
    }
    short8 ahi, alo;
#pragma unroll
    for (int j = 0; j < 8; j++) {
      float v = RELU ? fmaxf(av[j], 0.f) : av[j];
      ushort_t hi = bf16_rne(v);
      ahi[j] = (short)hi;
      alo[j] = (short)bf16_rne(v - bf16_to_f32(hi));
    }
#pragma unroll
    for (int t = 0; t < NT; t++) {
      const short8 bh = *(const short8*)(Bhi + (((size_t)ks * NT + t) * 64 + lane) * 8);
      const short8 bl = *(const short8*)(Blo + (((size_t)ks * NT + t) * 64 + lane) * 8);
      acc[t] = __builtin_amdgcn_mfma_f32_16x16x32_bf16(ahi, bh, acc[t], 0, 0, 0);
      acc[t] = __builtin_amdgcn_mfma_f32_16x16x32_bf16(ahi, bl, acc[t], 0, 0, 0);
      acc[t] = __builtin_amdgcn_mfma_f32_16x16x32_bf16(alo, bh, acc[t], 0, 0, 0);
    }
  }

  // D layout: col = lane&15 (=m), row_in_tile = q*4 + r
  int zrow = row0 + q * 4;
#pragma unroll
  for (int r = 0; r < 4; r++) {
    if (zrow + r < M) {
#pragma unroll
      for (int t = 0; t < NT; t++)
        Z[(size_t)(zrow + r) * NC + t * 16 + m] = acc[t][r];
    }
  }
}

// ---- CSR aggregation: out[i] = bias + z[i] + sum_{e in in(i)} z[src_e] ------
__global__ __launch_bounds__(256) void k_agg128(const float* __restrict__ z,
                                                const int* __restrict__ csr,
                                                const int* __restrict__ offs,
                                                const float* __restrict__ bias,
                                                float* __restrict__ out, int N) {
  int t = threadIdx.x;
  int node = blockIdx.x * 8 + (t >> 5);
  if (node >= N) return;
  int c = (t & 31) * 4;
  float4 v = *(const float4*)&z[(size_t)node * 128 + c];
  float4 b = *(const float4*)&bias[c];
  v.x += b.x; v.y += b.y; v.z += b.z; v.w += b.w;
  int s = offs[node], e = offs[node + 1];
  for (int j = s; j < e; j++) {
    int srci = csr[j];
    float4 u = *(const float4*)&z[(size_t)srci * 128 + c];
    v.x += u.x; v.y += u.y; v.z += u.z; v.w += u.w;
  }
  *(float4*)&out[(size_t)node * 128 + c] = v;
}

__global__ __launch_bounds__(256) void k_agg64(const float* __restrict__ z,
                                               const int* __restrict__ csr,
                                               const int* __restrict__ offs,
                                               const float* __restrict__ bias,
                                               float* __restrict__ out, int N) {
  int t = threadIdx.x;
  int node = blockIdx.x * 16 + (t >> 4);
  if (node >= N) return;
  int c = (t & 15) * 4;
  float4 v = *(const float4*)&z[(size_t)node * 64 + c];
  float4 b = *(const float4*)&bias[c];
  v.x += b.x; v.y += b.y; v.z += b.z; v.w += b.w;
  int s = offs[node], e = offs[node + 1];
  for (int j = s; j < e; j++) {
    int srci = csr[j];
    float4 u = *(const float4*)&z[(size_t)srci * 64 + c];
    v.x += u.x; v.y += u.y; v.z += u.z; v.w += u.w;
  }
  *(float4*)&out[(size_t)node * 64 + c] = v;
}

// ---------------------------------------------------------------------------
extern "C" void kernel_launch(void* const* d_in, const int* in_sizes, int n_in,
                              void* d_out, int out_size, void* d_ws, size_t ws_size,
                              hipStream_t stream) {
  const float* x  = (const float*)d_in[0];
  const void* edges = d_in[1];
  const float* W1 = (const float*)d_in[2];
  const float* b1 = (const float*)d_in[3];
  const float* W2 = (const float*)d_in[4];
  const float* b2 = (const float*)d_in[5];
  const float* W3 = (const float*)d_in[6];
  const float* b3 = (const float*)d_in[7];
  float* out = (float*)d_out;

  int N = in_sizes[0] / 128;   // 100000
  int E = in_sizes[1] / 2;     // 600000

  // workspace layout
  char* w = (char*)d_ws;
  size_t off = 0;
  auto alloc = [&](size_t bytes) -> void* {
    void* p = w + off;
    off = (off + bytes + 255) & ~(size_t)255;
    return p;
  };
  size_t curBytes = ((size_t)N * 4 + 255) & ~(size_t)255;
  int*   cursor = (int*)alloc(curBytes);     // also degree counts
  int*   flag   = (int*)alloc(4);            // adjacent: one memset covers both
  int*   src32  = (int*)alloc((size_t)E * 4);
  int*   dst32  = (int*)alloc((size_t)E * 4);
  int*   csr    = (int*)alloc((size_t)E * 4);
  int*   offs   = (int*)alloc((size_t)(N + 1) * 4);
  int*   bsum   = (int*)alloc(4096);
  ushort_t* h1  = (ushort_t*)alloc(16384 * 2);
  ushort_t* l1  = (ushort_t*)alloc(16384 * 2);
  ushort_t* h2  = (ushort_t*)alloc(16384 * 2);
  ushort_t* l2  = (ushort_t*)alloc(16384 * 2);
  ushort_t* h3  = (ushort_t*)alloc(8192 * 2);
  ushort_t* l3  = (ushort_t*)alloc(8192 * 2);
  float* z      = (float*)alloc((size_t)N * 128 * 4);
  float* a      = (float*)alloc((size_t)N * 128 * 4);  // a1, reused as a2

  int ge = (E + 255) / 256;
  int nb = (N + 1023) / 1024;

  // zero cursor+flag in one memset; then edge normalization + CSR build
  hipMemsetAsync(cursor, 0, curBytes + 4, stream);
  k_detect<<<4, 256, 0, stream>>>((const int*)edges, flag, E);
  k_convert<<<ge, 256, 0, stream>>>(edges, flag, src32, dst32, cursor, E);
  k_scan1<<<nb, 256, 0, stream>>>(cursor, offs, bsum, N);
  k_scan2<<<1, 128, 0, stream>>>(bsum, nb);
  k_scan3<<<nb, 256, 0, stream>>>(offs, bsum, cursor, N, E);
  k_fill<<<ge, 256, 0, stream>>>(src32, dst32, cursor, csr, E);
  k_repack<<<160, 256, 0, stream>>>(W1, W2, W3, h1, l1, h2, l2, h3, l3);

  int gm = (N + 63) / 64;
  // layer 1: z = x@W1 ; a1 = b1 + z + agg(z)
  k_gemm_mfma<128, false><<<gm, 256, 0, stream>>>(x, h1, l1, z, N);
  k_agg128<<<(N + 7) / 8, 256, 0, stream>>>(z, csr, offs, b1, a, N);
  // layer 2: z = relu(a1)@W2 ; a2 = b2 + z + agg(z)
  k_gemm_mfma<128, true><<<gm, 256, 0, stream>>>(a, h2, l2, z, N);
  k_agg128<<<(N + 7) / 8, 256, 0, stream>>>(z, csr, offs, b2, a, N);
  // layer 3: z = relu(a2)@W3 ; out = b3 + z + agg(z)   (no final relu)
  k_gemm_mfma<64, true><<<gm, 256, 0, stream>>>(a, h3, l3, z, N);
  k_agg64<<<(N + 15) / 16, 256, 0, stream>>>(z, csr, offs, b3, out, N);
}

// Round 3
// 369.350 us; speedup vs baseline: 1.2179x; 1.0684x over previous
//
#include <hip/hip_runtime.h>

// ---------------------------------------------------------------------------
// GIN 3-layer: h_{l+1} = act((h + agg(h)) @ W + b)
// Restructured: z = act(h) @ W ; a = b + z + agg(z)   (agg commutes with W)
// Layers 2,3: agg fused into GEMM prologue (a lives in LDS only).
// GEMM = split-bf16 MFMA (a_hi*w_hi + a_hi*w_lo + a_lo*w_hi, fp32 acc).
// ---------------------------------------------------------------------------

typedef __attribute__((ext_vector_type(8))) short short8;
typedef __attribute__((ext_vector_type(4))) float f32x4;
typedef unsigned short ushort_t;
typedef unsigned int uint_t;

__device__ inline ushort_t bf16_rne(float f) {
  uint_t u = __float_as_uint(f);
  uint_t r = (u + 0x7FFFu + ((u >> 16) & 1u)) >> 16;
  return (ushort_t)r;
}
__device__ inline float bf16_to_f32(ushort_t h) {
  return __uint_as_float(((uint_t)h) << 16);
}

// ---- edge dtype detection: int64 (reference decl) vs int32 (JAX x64-off) ----
__global__ __launch_bounds__(256) void k_detect(const int* __restrict__ ew,
                                                int* __restrict__ flag, int E) {
  int i = blockIdx.x * 256 + threadIdx.x;   // grid=4 -> i in [0,1024)
  int idx = 2 * i + 1;
  if (idx < 2 * E) {
    if (ew[idx] != 0) atomicOr(flag, 1);    // nonzero odd word => int32 layout
  }
}

// ---- CSR build (reads edges directly, no staging) ---------------------------
__global__ __launch_bounds__(256) void k_hist(const void* __restrict__ edges,
                                              const int* __restrict__ flag,
                                              int* __restrict__ counts, int E) {
  int e = blockIdx.x * 256 + threadIdx.x;
  if (e >= E) return;
  int d;
  if (*flag) d = ((const int*)edges)[E + e];
  else       d = (int)((const long long*)edges)[E + e];
  atomicAdd(&counts[d], 1);
}

__global__ __launch_bounds__(256) void k_scan1(const int* __restrict__ counts,
                                               int* __restrict__ offs,
                                               int* __restrict__ bsum, int N) {
  __shared__ int s[256];
  int t = threadIdx.x;
  int base = blockIdx.x * 1024 + t * 4;
  int c0 = 0, c1 = 0, c2 = 0, c3 = 0;
  if (base + 0 < N) c0 = counts[base + 0];
  if (base + 1 < N) c1 = counts[base + 1];
  if (base + 2 < N) c2 = counts[base + 2];
  if (base + 3 < N) c3 = counts[base + 3];
  int mySum = c0 + c1 + c2 + c3;
  s[t] = mySum;
  __syncthreads();
  for (int d = 1; d < 256; d <<= 1) {
    int v = (t >= d) ? s[t - d] : 0;
    __syncthreads();
    s[t] += v;
    __syncthreads();
  }
  int excl = s[t] - mySum;
  if (base + 0 < N) offs[base + 0] = excl;
  if (base + 1 < N) offs[base + 1] = excl + c0;
  if (base + 2 < N) offs[base + 2] = excl + c0 + c1;
  if (base + 3 < N) offs[base + 3] = excl + c0 + c1 + c2;
  if (t == 255) bsum[blockIdx.x] = s[255];
}

__global__ __launch_bounds__(128) void k_scan2(int* __restrict__ bsum, int nb) {
  __shared__ int s[128];
  int t = threadIdx.x;
  int v = (t < nb) ? bsum[t] : 0;
  s[t] = v;
  __syncthreads();
  for (int d = 1; d < 128; d <<= 1) {
    int u = (t >= d) ? s[t - d] : 0;
    __syncthreads();
    s[t] += u;
    __syncthreads();
  }
  if (t < nb) bsum[t] = s[t] - v;
}

__global__ __launch_bounds__(256) void k_scan3(int* __restrict__ offs,
                                               const int* __restrict__ bsum,
                                               int* __restrict__ cursor,
                                               int N, int E) {
  int t = threadIdx.x;
  int add = bsum[blockIdx.x];
  int base = blockIdx.x * 1024 + t * 4;
#pragma unroll
  for (int j = 0; j < 4; j++) {
    int i = base + j;
    if (i < N) { int v = offs[i] + add; offs[i] = v; cursor[i] = v; }
  }
  if (blockIdx.x == 0 && t == 0) offs[N] = E;
}

__global__ __launch_bounds__(256) void k_fill(const void* __restrict__ edges,
                                              const int* __restrict__ flag,
                                              int* __restrict__ cursor,
                                              int* __restrict__ csr, int E) {
  int e = blockIdx.x * 256 + threadIdx.x;
  if (e >= E) return;
  int s, d;
  if (*flag) {
    const int* p = (const int*)edges;
    s = p[e]; d = p[E + e];
  } else {
    const long long* p = (const long long*)edges;
    s = (int)p[e]; d = (int)p[E + e];
  }
  int pos = atomicAdd(&cursor[d], 1);
  csr[pos] = s;
}

// ---- W repack into MFMA B-fragment order (hi/lo split bf16) -----------------
// rep[((ks*NT + tile)*64 + lane)*8 + j] = W[ks*32 + (lane>>4)*8 + j][tile*16 + (lane&15)]
__global__ __launch_bounds__(256) void k_repack(
    const float* __restrict__ W1, const float* __restrict__ W2,
    const float* __restrict__ W3,
    ushort_t* __restrict__ h1, ushort_t* __restrict__ l1,
    ushort_t* __restrict__ h2, ushort_t* __restrict__ l2,
    ushort_t* __restrict__ h3, ushort_t* __restrict__ l3) {
  int idx = blockIdx.x * 256 + threadIdx.x;
  const float* W; ushort_t* H; ushort_t* L; int NC; int i;
  if (idx < 16384)      { W = W1; H = h1; L = l1; NC = 128; i = idx; }
  else if (idx < 32768) { W = W2; H = h2; L = l2; NC = 128; i = idx - 16384; }
  else if (idx < 40960) { W = W3; H = h3; L = l3; NC = 64;  i = idx - 32768; }
  else return;
  int j = i & 7;
  int lane = (i >> 3) & 63;
  int NT = NC >> 4;
  int tile = (i >> 9) & (NT - 1);
  int ks = i >> (9 + (NC == 128 ? 3 : 2));
  int k = ks * 32 + (lane >> 4) * 8 + j;
  int n = tile * 16 + (lane & 15);
  float v = W[(size_t)k * NC + n];
  ushort_t hi = bf16_rne(v);
  ushort_t lo = bf16_rne(v - bf16_to_f32(hi));
  H[i] = hi; L[i] = lo;
}

// ---- split-bf16 MFMA GEMM (layer 1): Z = A @ W, A read from global ----------
template <int NC, bool RELU>
__global__ __launch_bounds__(256) void k_gemm_mfma(
    const float* __restrict__ A, const ushort_t* __restrict__ Bhi,
    const ushort_t* __restrict__ Blo, float* __restrict__ Z, int M) {
  constexpr int NT = NC / 16;
  int lane = threadIdx.x & 63;
  int wave = threadIdx.x >> 6;
  int row0 = blockIdx.x * 64 + wave * 16;
  int m = lane & 15;
  int q = lane >> 4;
  int grow = row0 + m;
  bool rowok = (grow < M);

  f32x4 acc[NT];
#pragma unroll
  for (int t = 0; t < NT; t++) { acc[t][0] = 0.f; acc[t][1] = 0.f; acc[t][2] = 0.f; acc[t][3] = 0.f; }

  const float* arow = A + (size_t)grow * 128 + q * 8;

#pragma unroll
  for (int ks = 0; ks < 4; ks++) {
    float av[8];
    if (rowok) {
      *(float4*)(av)     = *(const float4*)(arow + ks * 32);
      *(float4*)(av + 4) = *(const float4*)(arow + ks * 32 + 4);
    } else {
#pragma unroll
      for (int j = 0; j < 8; j++) av[j] = 0.f;
    }
    short8 ahi, alo;
#pragma unroll
    for (int j = 0; j < 8; j++) {
      float v = RELU ? fmaxf(av[j], 0.f) : av[j];
      ushort_t hi = bf16_rne(v);
      ahi[j] = (short)hi;
      alo[j] = (short)bf16_rne(v - bf16_to_f32(hi));
    }
#pragma unroll
    for (int t = 0; t < NT; t++) {
      const short8 bh = *(const short8*)(Bhi + (((size_t)ks * NT + t) * 64 + lane) * 8);
      const short8 bl = *(const short8*)(Blo + (((size_t)ks * NT + t) * 64 + lane) * 8);
      acc[t] = __builtin_amdgcn_mfma_f32_16x16x32_bf16(ahi, bh, acc[t], 0, 0, 0);
      acc[t] = __builtin_amdgcn_mfma_f32_16x16x32_bf16(ahi, bl, acc[t], 0, 0, 0);
      acc[t] = __builtin_amdgcn_mfma_f32_16x16x32_bf16(alo, bh, acc[t], 0, 0, 0);
    }
  }

  int zrow = row0 + q * 4;
#pragma unroll
  for (int r = 0; r < 4; r++) {
    if (zrow + r < M) {
#pragma unroll
      for (int t = 0; t < NT; t++)
        Z[(size_t)(zrow + r) * NC + t * 16 + m] = acc[t][r];
    }
  }
}

// ---- fused agg + GEMM (layers 2,3): --------------------------------------
// a = bias + Zin + agg(Zin) into LDS; then Zout = relu(a) @ W via MFMA.
template <int NC>
__global__ __launch_bounds__(256) void k_fused(
    const float* __restrict__ Zin, const int* __restrict__ csr,
    const int* __restrict__ offs, const float* __restrict__ bias,
    const ushort_t* __restrict__ Bhi, const ushort_t* __restrict__ Blo,
    float* __restrict__ Zout, int M) {
  constexpr int NT = NC / 16;
  constexpr int LDA = 136;                    // 128 + 8 pad (16B-aligned rows)
  __shared__ float alds[64 * LDA];
  int t = threadIdx.x;
  int row0 = blockIdx.x * 64;

  // ---- phase 1: aggregate into LDS (half-wave per node, 8 nodes each) ----
  {
    int half = t >> 5;                        // 0..7
    int c = (t & 31) * 4;
    float4 bv = *(const float4*)&bias[c];
    for (int g = 0; g < 8; g++) {
      int r = g * 8 + half;
      int node = row0 + r;
      float4 v = make_float4(0.f, 0.f, 0.f, 0.f);
      if (node < M) {
        v = *(const float4*)&Zin[(size_t)node * 128 + c];
        v.x += bv.x; v.y += bv.y; v.z += bv.z; v.w += bv.w;
        int s = offs[node], e = offs[node + 1];
        int j = s;
        for (; j + 4 <= e; j += 4) {          // 4 gathers in flight
          int i0 = csr[j], i1 = csr[j + 1], i2 = csr[j + 2], i3 = csr[j + 3];
          float4 u0 = *(const float4*)&Zin[(size_t)i0 * 128 + c];
          float4 u1 = *(const float4*)&Zin[(size_t)i1 * 128 + c];
          float4 u2 = *(const float4*)&Zin[(size_t)i2 * 128 + c];
          float4 u3 = *(const float4*)&Zin[(size_t)i3 * 128 + c];
          v.x += u0.x + u1.x + u2.x + u3.x;
          v.y += u0.y + u1.y + u2.y + u3.y;
          v.z += u0.z + u1.z + u2.z + u3.z;
          v.w += u0.w + u1.w + u2.w + u3.w;
        }
        for (; j < e; j++) {
          int i0 = csr[j];
          float4 u = *(const float4*)&Zin[(size_t)i0 * 128 + c];
          v.x += u.x; v.y += u.y; v.z += u.z; v.w += u.w;
        }
      }
      *(float4*)&alds[r * LDA + c] = v;       // rows >= M get zeros
    }
  }
  __syncthreads();

  // ---- phase 2: Zout = relu(a) @ W ----
  int lane = t & 63;
  int wave = t >> 6;
  int m = lane & 15;
  int q = lane >> 4;
  int lrow = wave * 16 + m;

  f32x4 acc[NT];
#pragma unroll
  for (int tt = 0; tt < NT; tt++) { acc[tt][0] = 0.f; acc[tt][1] = 0.f; acc[tt][2] = 0.f; acc[tt][3] = 0.f; }

#pragma unroll
  for (int ks = 0; ks < 4; ks++) {
    float av[8];
    *(float4*)(av)     = *(const float4*)&alds[lrow * LDA + ks * 32 + q * 8];
    *(float4*)(av + 4) = *(const float4*)&alds[lrow * LDA + ks * 32 + q * 8 + 4];
    short8 ahi, alo;
#pragma unroll
    for (int j = 0; j < 8; j++) {
      float v = fmaxf(av[j], 0.f);            // relu (both fused layers)
      ushort_t hi = bf16_rne(v);
      ahi[j] = (short)hi;
      alo[j] = (short)bf16_rne(v - bf16_to_f32(hi));
    }
#pragma unroll
    for (int tt = 0; tt < NT; tt++) {
      const short8 bh = *(const short8*)(Bhi + (((size_t)ks * NT + tt) * 64 + lane) * 8);
      const short8 bl = *(const short8*)(Blo + (((size_t)ks * NT + tt) * 64 + lane) * 8);
      acc[tt] = __builtin_amdgcn_mfma_f32_16x16x32_bf16(ahi, bh, acc[tt], 0, 0, 0);
      acc[tt] = __builtin_amdgcn_mfma_f32_16x16x32_bf16(ahi, bl, acc[tt], 0, 0, 0);
      acc[tt] = __builtin_amdgcn_mfma_f32_16x16x32_bf16(alo, bh, acc[tt], 0, 0, 0);
    }
  }

  int zrow = row0 + wave * 16 + q * 4;
#pragma unroll
  for (int r = 0; r < 4; r++) {
    if (zrow + r < M) {
#pragma unroll
      for (int tt = 0; tt < NT; tt++)
        Zout[(size_t)(zrow + r) * NC + tt * 16 + m] = acc[tt][r];
    }
  }
}

// ---- final CSR aggregation (64 cols): out = b + z + agg(z) ------------------
__global__ __launch_bounds__(256) void k_agg64(const float* __restrict__ z,
                                               const int* __restrict__ csr,
                                               const int* __restrict__ offs,
                                               const float* __restrict__ bias,
                                               float* __restrict__ out, int N) {
  int t = threadIdx.x;
  int node = blockIdx.x * 16 + (t >> 4);
  if (node >= N) return;
  int c = (t & 15) * 4;
  float4 v = *(const float4*)&z[(size_t)node * 64 + c];
  float4 b = *(const float4*)&bias[c];
  v.x += b.x; v.y += b.y; v.z += b.z; v.w += b.w;
  int s = offs[node], e = offs[node + 1];
  int j = s;
  for (; j + 4 <= e; j += 4) {
    int i0 = csr[j], i1 = csr[j + 1], i2 = csr[j + 2], i3 = csr[j + 3];
    float4 u0 = *(const float4*)&z[(size_t)i0 * 64 + c];
    float4 u1 = *(const float4*)&z[(size_t)i1 * 64 + c];
    float4 u2 = *(const float4*)&z[(size_t)i2 * 64 + c];
    float4 u3 = *(const float4*)&z[(size_t)i3 * 64 + c];
    v.x += u0.x + u1.x + u2.x + u3.x;
    v.y += u0.y + u1.y + u2.y + u3.y;
    v.z += u0.z + u1.z + u2.z + u3.z;
    v.w += u0.w + u1.w + u2.w + u3.w;
  }
  for (; j < e; j++) {
    int i0 = csr[j];
    float4 u = *(const float4*)&z[(size_t)i0 * 64 + c];
    v.x += u.x; v.y += u.y; v.z += u.z; v.w += u.w;
  }
  *(float4*)&out[(size_t)node * 64 + c] = v;
}

// ---------------------------------------------------------------------------
extern "C" void kernel_launch(void* const* d_in, const int* in_sizes, int n_in,
                              void* d_out, int out_size, void* d_ws, size_t ws_size,
                              hipStream_t stream) {
  const float* x  = (const float*)d_in[0];
  const void* edges = d_in[1];
  const float* W1 = (const float*)d_in[2];
  const float* b1 = (const float*)d_in[3];
  const float* W2 = (const float*)d_in[4];
  const float* b2 = (const float*)d_in[5];
  const float* W3 = (const float*)d_in[6];
  const float* b3 = (const float*)d_in[7];
  float* out = (float*)d_out;

  int N = in_sizes[0] / 128;   // 100000
  int E = in_sizes[1] / 2;     // 600000

  char* w = (char*)d_ws;
  size_t off = 0;
  auto alloc = [&](size_t bytes) -> void* {
    void* p = w + off;
    off = (off + bytes + 255) & ~(size_t)255;
    return p;
  };
  size_t curBytes = ((size_t)N * 4 + 255) & ~(size_t)255;
  int*   cursor = (int*)alloc(curBytes);     // degree counts, then fill cursor
  int*   flag   = (int*)alloc(4);            // adjacent: one memset covers both
  int*   csr    = (int*)alloc((size_t)E * 4);
  int*   offs   = (int*)alloc((size_t)(N + 1) * 4);
  int*   bsum   = (int*)alloc(4096);
  ushort_t* h1  = (ushort_t*)alloc(16384 * 2);
  ushort_t* l1  = (ushort_t*)alloc(16384 * 2);
  ushort_t* h2  = (ushort_t*)alloc(16384 * 2);
  ushort_t* l2  = (ushort_t*)alloc(16384 * 2);
  ushort_t* h3  = (ushort_t*)alloc(8192 * 2);
  ushort_t* l3  = (ushort_t*)alloc(8192 * 2);
  float* z1     = (float*)alloc((size_t)N * 128 * 4);
  float* z2     = (float*)alloc((size_t)N * 128 * 4);
  float* z3     = z1;                         // reuse (N x 64 fits)

  int ge = (E + 255) / 256;
  int nb = (N + 1023) / 1024;

  hipMemsetAsync(cursor, 0, curBytes + 4, stream);
  k_detect<<<4, 256, 0, stream>>>((const int*)edges, flag, E);
  k_hist<<<ge, 256, 0, stream>>>(edges, flag, cursor, E);
  k_scan1<<<nb, 256, 0, stream>>>(cursor, offs, bsum, N);
  k_scan2<<<1, 128, 0, stream>>>(bsum, nb);
  k_scan3<<<nb, 256, 0, stream>>>(offs, bsum, cursor, N, E);
  k_fill<<<ge, 256, 0, stream>>>(edges, flag, cursor, csr, E);
  k_repack<<<160, 256, 0, stream>>>(W1, W2, W3, h1, l1, h2, l2, h3, l3);

  int gm = (N + 63) / 64;
  // layer 1: z1 = x @ W1
  k_gemm_mfma<128, false><<<gm, 256, 0, stream>>>(x, h1, l1, z1, N);
  // layer 2 fused: a1 = b1 + z1 + agg(z1) (LDS); z2 = relu(a1) @ W2
  k_fused<128><<<gm, 256, 0, stream>>>(z1, csr, offs, b1, h2, l2, z2, N);
  // layer 3 fused: a2 = b2 + z2 + agg(z2) (LDS); z3 = relu(a2) @ W3
  k_fused<64><<<gm, 256, 0, stream>>>(z2, csr, offs, b2, h3, l3, z3, N);
  // final agg: out = b3 + z3 + agg(z3)
  k_agg64<<<(N + 15) / 16, 256, 0, stream>>>(z3, csr, offs, b3, out, N);
}